// Round 6
// baseline (118.912 us; speedup 1.0000x reference)
//
#include <hip/hip_runtime.h>
#include <float.h>

#define BB 8
#define TT 20
#define NN 512
#define DD 64
#define BT (BB*TT)

typedef __bf16 bf16x8 __attribute__((ext_vector_type(8)));
typedef float f32x4 __attribute__((ext_vector_type(4)));

// ---------- K1: per-slice (64 nodes) transpose + partial mean + colinfo + compaction
//              + zero-fill of masked-out output rows ----------
__global__ __launch_bounds__(256) void kpre(const float* __restrict__ h,
                                            const float* __restrict__ vel,
                                            const int* __restrict__ mask,
                                            __bf16* __restrict__ ht,
                                            float* __restrict__ hpart,
                                            int* __restrict__ cpart,
                                            float4* __restrict__ colinfo,
                                            int* __restrict__ rows,
                                            int* __restrict__ cnt,
                                            float* __restrict__ out) {
    int bx = blockIdx.x;
    int bt = bx >> 3, slice = bx & 7;
    int n0 = slice * 64;
    int tid = threadIdx.x;
    const float* hp = h + ((size_t)bt * NN + n0) * DD;
    const int* mp = mask + (size_t)bt * NN + n0;
    short* htp = (short*)(ht + (size_t)bt * DD * NN) + n0;

    __shared__ __bf16 t[64][72];
    __shared__ float sred[16][64];
    __shared__ int smask[64];

    int d4 = (tid & 15) << 2;
    int nl0 = tid >> 4;
    float s0 = 0.f, s1 = 0.f, s2 = 0.f, s3 = 0.f;
#pragma unroll
    for (int it = 0; it < 4; ++it) {
        int nl = it * 16 + nl0;
        float4 v = *(const float4*)(hp + (size_t)nl * DD + d4);
        if (mp[nl]) { s0 += v.x; s1 += v.y; s2 += v.z; s3 += v.w; }
        t[d4 + 0][nl] = (__bf16)v.x;
        t[d4 + 1][nl] = (__bf16)v.y;
        t[d4 + 2][nl] = (__bf16)v.z;
        t[d4 + 3][nl] = (__bf16)v.w;
    }
    int g = tid >> 4;
    sred[g][d4 + 0] = s0; sred[g][d4 + 1] = s1;
    sred[g][d4 + 2] = s2; sred[g][d4 + 3] = s3;
    if (tid < 64) smask[tid] = mp[tid];
    __syncthreads();
#pragma unroll
    for (int it = 0; it < 4; ++it) {
        int idx = it * 256 + tid;
        int d = idx >> 4, s = idx & 15;
        short4 v4 = *(const short4*)&t[d][4 * s];
        *(short4*)(htp + (size_t)d * NN + 4 * s) = v4;
    }
    // zero-fill out rows with mask==0 (16 float4 per row, 16 threads per row)
    float4* ob = (float4*)(out + ((size_t)bt * NN + n0) * DD);
    float4 z4 = {0.f, 0.f, 0.f, 0.f};
#pragma unroll
    for (int it = 0; it < 4; ++it) {
        int idx = it * 256 + tid;
        int r = idx >> 4, v = idx & 15;
        if (!smask[r]) ob[(size_t)r * 16 + v] = z4;
    }
    if (tid < 64) {
        float tot = 0.f;
#pragma unroll
        for (int k = 0; k < 16; ++k) tot += sred[k][tid];
        hpart[(size_t)bx * DD + tid] = tot;
    }
    if (tid < 64) {                       // wave 0: colinfo + compaction
        int j = n0 + tid;
        float2 v = ((const float2*)vel)[(size_t)bt * NN + j];
        int m = smask[tid];
        float cz = m ? -(v.x * v.x + v.y * v.y) : -3e38f;
        colinfo[(size_t)bt * NN + j] = make_float4(v.x, v.y, cz, 0.f);
        unsigned long long bal = __ballot(m != 0);
        int pos = __popcll(bal & ((1ull << tid) - 1ull));
        int totc = __popcll(bal);
        int base = 0;
        if (tid == 0) { base = atomicAdd(&cnt[bt], totc); cpart[bx] = totc; }
        base = __shfl(base, 0, 64);
        if (m) rows[(size_t)bt * NN + base + pos] = j;
    }
}

// ---------- K2: fused spatial+temporal attention, MFMA, XCD-affine blocks ----------
// p = exp(adj_ij + 2 vi.vj - |vj|^2); per-row constants cancel in softmax.
// beta row computed inline from hpart; temporal sum folded into epilogue.
__global__ __launch_bounds__(512) void kfused(const float* __restrict__ adj,
                                              const float* __restrict__ vel,
                                              const float* __restrict__ h,
                                              const int* __restrict__ cnt,
                                              const int* __restrict__ rows,
                                              const float4* __restrict__ colinfo,
                                              const __bf16* __restrict__ ht,
                                              const float* __restrict__ hpart,
                                              const int* __restrict__ cpart,
                                              float* __restrict__ out) {
    // XCD-affinity: all 8 row-blocks of one bt on one XCD; XCD x owns b==x.
    int bx = blockIdx.x;
    int x = bx & 7;
    int m8 = bx >> 3;                  // 0..159
    int b = x, tt = m8 >> 3;
    int bt = b * TT + tt;
    int i0 = (m8 & 7) * 64;
    int n_act = cnt[bt];
    if (i0 >= n_act) return;

    int tid = threadIdx.x;
    int w = tid >> 6, lane = tid & 63;
    int rg = w >> 1, jh = w & 1;       // row-group 0..3, j-half 0..1
    int arow = lane & 15;              // A row / C col index
    int kg = lane >> 4;                // k-group 0..3

    __shared__ float4 ci[NN];
    __shared__ float comb[8][64][9];
    __shared__ float hm[TT][DD + 1];
    __shared__ float invc_s[TT];
    __shared__ float mb_s[TT];
    __shared__ float cf[TT];

    for (int idx = tid; idx < NN; idx += 512)
        ci[idx] = colinfo[(size_t)bt * NN + idx];

    // ---- inline beta row t: hm finalize -> row-t Gram -> softmax -> cf ----
    if (tid < TT) {
        int c = 0;
#pragma unroll
        for (int k = 0; k < 8; ++k) c += cpart[(b * TT + tid) * 8 + k];
        invc_s[tid] = 1.f / fmaxf((float)c, 1.f);
    }
    __syncthreads();
    for (int idx = tid; idx < TT * DD; idx += 512) {
        int u = idx >> 6, d = idx & 63;
        const float* pp = hpart + ((size_t)(b * TT + u) * 8) * DD + d;
        float s = 0.f;
#pragma unroll
        for (int k = 0; k < 8; ++k) s += pp[k * DD];
        hm[u][d] = s * invc_s[u];
    }
    __syncthreads();
    if (tid < TT) {
        float s = 0.f;
        for (int d = 0; d < DD; ++d) s += hm[tt][d] * hm[tid][d];
        mb_s[tid] = s;
    }
    __syncthreads();
    if (tid == 0) {
        float mx = -FLT_MAX;
        for (int u = 0; u < TT; ++u) mx = fmaxf(mx, mb_s[u]);
        float sum = 0.f, e[TT];
        for (int u = 0; u < TT; ++u) { e[u] = __expf(mb_s[u] - mx); sum += e[u]; }
        float inv = 1.f / sum;
        for (int u = 0; u < TT; ++u) cf[u] = e[u] * inv;
        cf[tt] += 1.f;                 // fold the identity (h) term
    }

    int slot = i0 + rg * 16 + arow;
    int slotc = slot < n_act ? slot : n_act - 1;
    int row = rows[(size_t)bt * NN + slotc];
    float2 rv = ((const float2*)vel)[(size_t)bt * NN + row];
    float vx2 = 2.f * rv.x, vy2 = 2.f * rv.y;

    const float* arowp = adj + ((size_t)bt * NN + row) * NN + jh * 256;
    const __bf16* htb = ht + (size_t)bt * DD * NN + jh * 256;

    f32x4 zero = {0.f, 0.f, 0.f, 0.f};
    f32x4 acc[4];
#pragma unroll
    for (int nt = 0; nt < 4; ++nt) acc[nt] = zero;
    float lsum = 0.f;
    __syncthreads();

    int jb = kg * 8;
    f32x4 a01 = __builtin_nontemporal_load((const f32x4*)(arowp + jb));
    f32x4 a23 = __builtin_nontemporal_load((const f32x4*)(arowp + jb + 4));
#pragma unroll
    for (int c = 0; c < 8; ++c) {
        f32x4 n01, n23;
        if (c < 7) {
            n01 = __builtin_nontemporal_load((const f32x4*)(arowp + jb + 32));
            n23 = __builtin_nontemporal_load((const f32x4*)(arowp + jb + 36));
        }
        const float4* ccp = &ci[jh * 256 + jb];
        float p[8];
#pragma unroll
        for (int e = 0; e < 8; ++e) {
            float av = (e < 4) ? a01[e] : a23[e - 4];
            float4 cc = ccp[e];
            float l = av + cc.z + vx2 * cc.x + vy2 * cc.y;
            p[e] = __expf(l);
        }
        lsum += ((p[0] + p[1]) + (p[2] + p[3])) + ((p[4] + p[5]) + (p[6] + p[7]));
        bf16x8 af;
#pragma unroll
        for (int e = 0; e < 8; ++e) af[e] = (__bf16)p[e];
#pragma unroll
        for (int nt = 0; nt < 4; ++nt) {
            bf16x8 bf = *(const bf16x8*)(htb + (size_t)(nt * 16 + arow) * NN + jb);
            acc[nt] = __builtin_amdgcn_mfma_f32_16x16x32_bf16(af, bf, acc[nt], 0, 0, 0);
        }
        jb += 32;
        a01 = n01; a23 = n23;
    }

    lsum += __shfl_xor(lsum, 16, 64);
    lsum += __shfl_xor(lsum, 32, 64);

    // exchange: jh0 finalizes regs {0,1} (stores {2,3}); jh1 finalizes {2,3} (stores {0,1})
    float* cb = &comb[w][lane][0];
    int sbase = jh == 0 ? 2 : 0;
#pragma unroll
    for (int nt = 0; nt < 4; ++nt) {
        cb[nt * 2 + 0] = acc[nt][sbase + 0];
        cb[nt * 2 + 1] = acc[nt][sbase + 1];
    }
    cb[8] = lsum;
    __syncthreads();
    const float* pb = &comb[rg * 2 + (jh ^ 1)][lane][0];
    int rbase = jh == 0 ? 0 : 2;
#pragma unroll
    for (int nt = 0; nt < 4; ++nt) {
        acc[nt][rbase + 0] += pb[nt * 2 + 0];
        acc[nt][rbase + 1] += pb[nt * 2 + 1];
    }
    lsum += pb[8];
    float inv = 1.0f / fmaxf(lsum, 1e-8f);

    float* op = out + (size_t)bt * NN * DD;
    const float* hb = h + (size_t)b * TT * NN * DD;
#pragma unroll
    for (int r = 0; r < 2; ++r) {
        int reg = rbase + r;
        int cr = kg * 4 + reg;
        int s2 = i0 + rg * 16 + cr;
        int r2 = __shfl(row, cr, 64);
        float iv = __shfl(inv, cr, 64);
        if (s2 < n_act) {
            const float* hrow = hb + (size_t)r2 * DD + arow;
            float t0 = 0.f, t1 = 0.f, t2 = 0.f, t3 = 0.f;
#pragma unroll
            for (int u = 0; u < TT; ++u) {
                float c = cf[u];
                const float* hu = hrow + (size_t)u * NN * DD;
                t0 += c * hu[0];
                t1 += c * hu[16];
                t2 += c * hu[32];
                t3 += c * hu[48];
            }
            op[(size_t)r2 * DD + 0  + arow] = t0 + acc[0][reg] * iv;
            op[(size_t)r2 * DD + 16 + arow] = t1 + acc[1][reg] * iv;
            op[(size_t)r2 * DD + 32 + arow] = t2 + acc[2][reg] * iv;
            op[(size_t)r2 * DD + 48 + arow] = t3 + acc[3][reg] * iv;
        }
    }
}

extern "C" void kernel_launch(void* const* d_in, const int* in_sizes, int n_in,
                              void* d_out, int out_size, void* d_ws, size_t ws_size,
                              hipStream_t stream) {
    const float* h   = (const float*)d_in[0];
    const float* vel = (const float*)d_in[1];
    const float* adj = (const float*)d_in[2];
    const int* mask  = (const int*)d_in[3];
    float* out = (float*)d_out;

    char* ws = (char*)d_ws;
    __bf16* ht      = (__bf16*)ws;                       ws += (size_t)BT * DD * NN * 2;
    float4* colinfo = (float4*)ws;                       ws += (size_t)BT * NN * 16;
    float* hpart    = (float*)ws;                        ws += (size_t)BT * 8 * DD * 4;
    int* cpart      = (int*)ws;                          ws += (size_t)BT * 8 * 4;
    int* rows       = (int*)ws;                          ws += (size_t)BT * NN * 4;
    int* cnt        = (int*)ws;

    (void)hipMemsetAsync(cnt, 0, BT * sizeof(int), stream);
    kpre<<<BT * 8, 256, 0, stream>>>(h, vel, mask, ht, hpart, cpart, colinfo, rows, cnt, out);
    kfused<<<BT * 8, 512, 0, stream>>>(adj, vel, h, cnt, rows, colinfo, ht, hpart, cpart, out);
}

// Round 7
// 97.419 us; speedup vs baseline: 1.2206x; 1.2206x over previous
//
#include <hip/hip_runtime.h>
#include <float.h>

#define BB 8
#define TT 20
#define NN 512
#define DD 64
#define BT (BB*TT)

typedef __bf16 bf16x8 __attribute__((ext_vector_type(8)));
typedef float f32x4 __attribute__((ext_vector_type(4)));

// ---------- K1: per-slice (64 nodes) transpose + partial mean + colinfo + compaction ----------
__global__ __launch_bounds__(256) void kpre(const float* __restrict__ h,
                                            const float* __restrict__ vel,
                                            const int* __restrict__ mask,
                                            __bf16* __restrict__ ht,
                                            float* __restrict__ hpart,
                                            int* __restrict__ cpart,
                                            float4* __restrict__ colinfo,
                                            int* __restrict__ rows,
                                            int* __restrict__ cnt) {
    int bx = blockIdx.x;
    int bt = bx >> 3, slice = bx & 7;
    int n0 = slice * 64;
    int tid = threadIdx.x;
    const float* hp = h + ((size_t)bt * NN + n0) * DD;
    const int* mp = mask + (size_t)bt * NN + n0;
    short* htp = (short*)(ht + (size_t)bt * DD * NN) + n0;

    __shared__ __bf16 t[64][72];
    __shared__ float sred[16][64];

    int d4 = (tid & 15) << 2;
    int nl0 = tid >> 4;
    float s0 = 0.f, s1 = 0.f, s2 = 0.f, s3 = 0.f;
#pragma unroll
    for (int it = 0; it < 4; ++it) {
        int nl = it * 16 + nl0;
        float4 v = *(const float4*)(hp + (size_t)nl * DD + d4);
        if (mp[nl]) { s0 += v.x; s1 += v.y; s2 += v.z; s3 += v.w; }
        t[d4 + 0][nl] = (__bf16)v.x;
        t[d4 + 1][nl] = (__bf16)v.y;
        t[d4 + 2][nl] = (__bf16)v.z;
        t[d4 + 3][nl] = (__bf16)v.w;
    }
    int g = tid >> 4;
    sred[g][d4 + 0] = s0; sred[g][d4 + 1] = s1;
    sred[g][d4 + 2] = s2; sred[g][d4 + 3] = s3;
    __syncthreads();
#pragma unroll
    for (int it = 0; it < 4; ++it) {
        int idx = it * 256 + tid;
        int d = idx >> 4, s = idx & 15;
        short4 v4 = *(const short4*)&t[d][4 * s];
        *(short4*)(htp + (size_t)d * NN + 4 * s) = v4;
    }
    if (tid < 64) {
        float tot = 0.f;
#pragma unroll
        for (int k = 0; k < 16; ++k) tot += sred[k][tid];
        hpart[(size_t)bx * DD + tid] = tot;
    }
    if (tid < 64) {                       // wave 0: colinfo + compaction
        int j = n0 + tid;
        float2 v = ((const float2*)vel)[(size_t)bt * NN + j];
        int m = mp[tid];
        float cz = m ? -(v.x * v.x + v.y * v.y) : -3e38f;
        colinfo[(size_t)bt * NN + j] = make_float4(v.x, v.y, cz, 0.f);
        unsigned long long bal = __ballot(m != 0);
        int pos = __popcll(bal & ((1ull << tid) - 1ull));
        int totc = __popcll(bal);
        int base = 0;
        if (tid == 0) { base = atomicAdd(&cnt[bt], totc); cpart[bx] = totc; }
        base = __shfl(base, 0, 64);
        if (m) rows[(size_t)bt * NN + base + pos] = j;
    }
}

// ---------- K2: finalize hmean from partials, then beta = softmax(hmean hmean^T) ----------
__global__ __launch_bounds__(256) void kbeta(const float* __restrict__ hpart,
                                             const int* __restrict__ cpart,
                                             float* __restrict__ beta) {
    int b = blockIdx.x;
    int tid = threadIdx.x;
    __shared__ float hm[TT][DD];
    __shared__ float mb[TT][TT];
    __shared__ float invc[TT];
    if (tid < TT) {
        int c = 0;
#pragma unroll
        for (int k = 0; k < 8; ++k) c += cpart[(b * TT + tid) * 8 + k];
        invc[tid] = 1.f / fmaxf((float)c, 1.f);
    }
    __syncthreads();
    for (int idx = tid; idx < TT * DD; idx += 256) {
        int t = idx / DD, d = idx % DD;
        const float* pp = hpart + ((size_t)(b * TT + t) * 8) * DD + d;
        float s = 0.f;
#pragma unroll
        for (int k = 0; k < 8; ++k) s += pp[k * DD];
        hm[t][d] = s * invc[t];
    }
    __syncthreads();
    for (int p = tid; p < TT * TT; p += 256) {
        int t = p / TT, u = p % TT;
        float s = 0.f;
        for (int d = 0; d < DD; ++d) s += hm[t][d] * hm[u][d];
        mb[t][u] = s;
    }
    __syncthreads();
    if (tid < TT) {
        float mx = -FLT_MAX;
        for (int u = 0; u < TT; ++u) mx = fmaxf(mx, mb[tid][u]);
        float e[TT]; float sum = 0.f;
        for (int u = 0; u < TT; ++u) { e[u] = __expf(mb[tid][u] - mx); sum += e[u]; }
        float inv = 1.f / sum;
        for (int u = 0; u < TT; ++u)
            beta[((size_t)b * TT + tid) * TT + u] = e[u] * inv;
    }
}

// ---------- K3: out = (h + h_temporal) * mask ----------
__global__ __launch_bounds__(256) void ktemporal(const float* __restrict__ h,
                                                 const float* __restrict__ beta,
                                                 const int* __restrict__ mask,
                                                 float* __restrict__ out) {
    int b = blockIdx.x >> 6;
    int q = (blockIdx.x & 63) * 256 + threadIdx.x;   // 0..16383 float2 slots
    int n = q >> 5;
    __shared__ float cf[TT][TT];
    for (int idx = threadIdx.x; idx < TT * TT; idx += 256) {
        int t = idx / TT, u = idx % TT;
        cf[t][u] = beta[((size_t)b * TT + t) * TT + u] + (t == u ? 1.f : 0.f);
    }
    __syncthreads();
    const float2* hp = (const float2*)h + (size_t)b * TT * 16384;
    float2* op = (float2*)out + (size_t)b * TT * 16384;
    const int* mp = mask + (size_t)b * TT * NN;
    float2 hv[TT];
#pragma unroll
    for (int u = 0; u < TT; ++u) hv[u] = hp[(size_t)u * 16384 + q];
    float2 z = {0.f, 0.f};
#pragma unroll
    for (int t = 0; t < TT; ++t) {
        float2 a = z;
#pragma unroll
        for (int u = 0; u < TT; ++u) {
            float c = cf[t][u];
            a.x += c * hv[u].x; a.y += c * hv[u].y;
        }
        int m = mp[(size_t)t * NN + n];
        op[(size_t)t * 16384 + q] = m ? a : z;
    }
}

// ---------- K4: spatial attention, MFMA, XCD-affine, 2-deep adj prefetch ----------
// p = exp(adj_ij + 2 vi.vj - |vj|^2); per-row constants cancel in softmax.
__global__ __launch_bounds__(512) void kspatial(const float* __restrict__ adj,
                                                const float* __restrict__ vel,
                                                const int* __restrict__ cnt,
                                                const int* __restrict__ rows,
                                                const float4* __restrict__ colinfo,
                                                const __bf16* __restrict__ ht,
                                                float* __restrict__ out) {
    int bx = blockIdx.x;
    int x = bx & 7;
    int m8 = bx >> 3;                  // 0..159
    int bt = x * 20 + (m8 >> 3);
    int i0 = (m8 & 7) * 64;
    int n_act = cnt[bt];
    if (i0 >= n_act) return;

    int tid = threadIdx.x;
    int w = tid >> 6, lane = tid & 63;
    int rg = w >> 1, jh = w & 1;       // row-group 0..3, j-half 0..1
    int arow = lane & 15;              // A row / C col index
    int kg = lane >> 4;                // k-group 0..3

    __shared__ float4 ci[NN];
    __shared__ float comb[4][64][17];

    for (int idx = tid; idx < NN; idx += 512)
        ci[idx] = colinfo[(size_t)bt * NN + idx];

    int slot = i0 + rg * 16 + arow;
    int slotc = slot < n_act ? slot : n_act - 1;
    int row = rows[(size_t)bt * NN + slotc];
    float2 rv = ((const float2*)vel)[(size_t)bt * NN + row];
    float vx2 = 2.f * rv.x, vy2 = 2.f * rv.y;

    const float* arowp = adj + ((size_t)bt * NN + row) * NN + jh * 256;
    const __bf16* htb = ht + (size_t)bt * DD * NN + jh * 256;

    f32x4 zero = {0.f, 0.f, 0.f, 0.f};
    f32x4 acc[4];
#pragma unroll
    for (int nt = 0; nt < 4; ++nt) acc[nt] = zero;
    float lsum = 0.f;
    __syncthreads();

    // 2-deep prefetch: loads for iteration c issued at c-2 (fully unrolled,
    // constant indices -> registers, ~3 slots live at once)
    f32x4 a01[8], a23[8];
    {
        const f32x4* p0 = (const f32x4*)(arowp + kg * 8);
        a01[0] = __builtin_nontemporal_load(p0);
        a23[0] = __builtin_nontemporal_load(p0 + 1);
        a01[1] = __builtin_nontemporal_load(p0 + 8);
        a23[1] = __builtin_nontemporal_load(p0 + 9);
    }
#pragma unroll
    for (int c = 0; c < 8; ++c) {
        if (c < 6) {
            const f32x4* pn = (const f32x4*)(arowp + kg * 8 + (c + 2) * 32);
            a01[c + 2] = __builtin_nontemporal_load(pn);
            a23[c + 2] = __builtin_nontemporal_load(pn + 1);
        }
        int jb = kg * 8 + c * 32;
        const float4* ccp = &ci[jh * 256 + jb];
        float p[8];
#pragma unroll
        for (int e = 0; e < 8; ++e) {
            float av = (e < 4) ? a01[c][e] : a23[c][e - 4];
            float4 cc = ccp[e];
            float l = av + cc.z + vx2 * cc.x + vy2 * cc.y;
            p[e] = __expf(l);
        }
        lsum += ((p[0] + p[1]) + (p[2] + p[3])) + ((p[4] + p[5]) + (p[6] + p[7]));
        bf16x8 af;
#pragma unroll
        for (int e = 0; e < 8; ++e) af[e] = (__bf16)p[e];
#pragma unroll
        for (int nt = 0; nt < 4; ++nt) {
            bf16x8 bf = *(const bf16x8*)(htb + (size_t)(nt * 16 + arow) * NN + jb);
            acc[nt] = __builtin_amdgcn_mfma_f32_16x16x32_bf16(af, bf, acc[nt], 0, 0, 0);
        }
    }

    lsum += __shfl_xor(lsum, 16, 64);
    lsum += __shfl_xor(lsum, 32, 64);

    if (jh == 1) {
#pragma unroll
        for (int nt = 0; nt < 4; ++nt)
#pragma unroll
            for (int q = 0; q < 4; ++q)
                comb[rg][lane][nt * 4 + q] = acc[nt][q];
        comb[rg][lane][16] = lsum;
    }
    __syncthreads();
    if (jh == 0) {
#pragma unroll
        for (int nt = 0; nt < 4; ++nt)
#pragma unroll
            for (int q = 0; q < 4; ++q)
                acc[nt][q] += comb[rg][lane][nt * 4 + q];
        lsum += comb[rg][lane][16];
        float inv = 1.0f / fmaxf(lsum, 1e-8f);

        float* op = out + (size_t)bt * NN * DD;
#pragma unroll
        for (int q = 0; q < 4; ++q) {
            int cr = kg * 4 + q;
            int s2 = i0 + rg * 16 + cr;
            int r2 = __shfl(row, cr, 64);
            float iv = __shfl(inv, cr, 64);
            if (s2 < n_act) {
#pragma unroll
                for (int nt = 0; nt < 4; ++nt) {
                    size_t o = (size_t)r2 * DD + nt * 16 + arow;
                    op[o] = op[o] + acc[nt][q] * iv;
                }
            }
        }
    }
}

extern "C" void kernel_launch(void* const* d_in, const int* in_sizes, int n_in,
                              void* d_out, int out_size, void* d_ws, size_t ws_size,
                              hipStream_t stream) {
    const float* h   = (const float*)d_in[0];
    const float* vel = (const float*)d_in[1];
    const float* adj = (const float*)d_in[2];
    const int* mask  = (const int*)d_in[3];
    float* out = (float*)d_out;

    char* ws = (char*)d_ws;
    __bf16* ht      = (__bf16*)ws;                       ws += (size_t)BT * DD * NN * 2;
    float4* colinfo = (float4*)ws;                       ws += (size_t)BT * NN * 16;
    float* hpart    = (float*)ws;                        ws += (size_t)BT * 8 * DD * 4;
    int* cpart      = (int*)ws;                          ws += (size_t)BT * 8 * 4;
    float* beta     = (float*)ws;                        ws += (size_t)BB * TT * TT * 4;
    int* rows       = (int*)ws;                          ws += (size_t)BT * NN * 4;
    int* cnt        = (int*)ws;

    (void)hipMemsetAsync(cnt, 0, BT * sizeof(int), stream);
    kpre<<<BT * 8, 256, 0, stream>>>(h, vel, mask, ht, hpart, cpart, colinfo, rows, cnt);
    kbeta<<<BB, 256, 0, stream>>>(hpart, cpart, beta);
    ktemporal<<<BB * 64, 256, 0, stream>>>(h, beta, mask, out);
    kspatial<<<BT * 8, 512, 0, stream>>>(adj, vel, cnt, rows, colinfo, ht, out);
}

// Round 9
// 70.828 us; speedup vs baseline: 1.6789x; 1.3754x over previous
//
#include <hip/hip_runtime.h>
#include <float.h>

#define BB 8
#define TT 20
#define NN 512
#define DD 64
#define BT (BB*TT)

typedef __bf16 bf16x8 __attribute__((ext_vector_type(8)));
typedef float f32x4 __attribute__((ext_vector_type(4)));

// ---------- K1: per-slice (64 nodes) transpose + partial mean + colinfo + compaction ----------
__global__ __launch_bounds__(256) void kpre(const float* __restrict__ h,
                                            const float* __restrict__ vel,
                                            const int* __restrict__ mask,
                                            __bf16* __restrict__ ht,
                                            float* __restrict__ hpart,
                                            int* __restrict__ cpart,
                                            float4* __restrict__ colinfo,
                                            int* __restrict__ rows,
                                            int* __restrict__ cnt) {
    int bx = blockIdx.x;
    int bt = bx >> 3, slice = bx & 7;
    int n0 = slice * 64;
    int tid = threadIdx.x;
    const float* hp = h + ((size_t)bt * NN + n0) * DD;
    const int* mp = mask + (size_t)bt * NN + n0;
    short* htp = (short*)(ht + (size_t)bt * DD * NN) + n0;

    __shared__ __bf16 t[64][72];
    __shared__ float sred[16][64];

    int d4 = (tid & 15) << 2;
    int nl0 = tid >> 4;
    float s0 = 0.f, s1 = 0.f, s2 = 0.f, s3 = 0.f;
#pragma unroll
    for (int it = 0; it < 4; ++it) {
        int nl = it * 16 + nl0;
        float4 v = *(const float4*)(hp + (size_t)nl * DD + d4);
        if (mp[nl]) { s0 += v.x; s1 += v.y; s2 += v.z; s3 += v.w; }
        t[d4 + 0][nl] = (__bf16)v.x;
        t[d4 + 1][nl] = (__bf16)v.y;
        t[d4 + 2][nl] = (__bf16)v.z;
        t[d4 + 3][nl] = (__bf16)v.w;
    }
    int g = tid >> 4;
    sred[g][d4 + 0] = s0; sred[g][d4 + 1] = s1;
    sred[g][d4 + 2] = s2; sred[g][d4 + 3] = s3;
    __syncthreads();
#pragma unroll
    for (int it = 0; it < 4; ++it) {
        int idx = it * 256 + tid;
        int d = idx >> 4, s = idx & 15;
        short4 v4 = *(const short4*)&t[d][4 * s];
        *(short4*)(htp + (size_t)d * NN + 4 * s) = v4;
    }
    if (tid < 64) {
        float tot = 0.f;
#pragma unroll
        for (int k = 0; k < 16; ++k) tot += sred[k][tid];
        hpart[(size_t)bx * DD + tid] = tot;
    }
    if (tid < 64) {                       // wave 0: colinfo + compaction
        int j = n0 + tid;
        float2 v = ((const float2*)vel)[(size_t)bt * NN + j];
        int m = mp[tid];
        float cz = m ? -(v.x * v.x + v.y * v.y) : -3e38f;
        colinfo[(size_t)bt * NN + j] = make_float4(v.x, v.y, cz, 0.f);
        unsigned long long bal = __ballot(m != 0);
        int pos = __popcll(bal & ((1ull << tid) - 1ull));
        int totc = __popcll(bal);
        int base = 0;
        if (tid == 0) { base = atomicAdd(&cnt[bt], totc); cpart[bx] = totc; }
        base = __shfl(base, 0, 64);
        if (m) rows[(size_t)bt * NN + base + pos] = j;
    }
}

// ---------- K2: finalize hmean from partials, then beta = softmax(hmean hmean^T) ----------
__global__ __launch_bounds__(256) void kbeta(const float* __restrict__ hpart,
                                             const int* __restrict__ cpart,
                                             float* __restrict__ beta) {
    int b = blockIdx.x;
    int tid = threadIdx.x;
    __shared__ float hm[TT][DD];
    __shared__ float mb[TT][TT];
    __shared__ float invc[TT];
    if (tid < TT) {
        int c = 0;
#pragma unroll
        for (int k = 0; k < 8; ++k) c += cpart[(b * TT + tid) * 8 + k];
        invc[tid] = 1.f / fmaxf((float)c, 1.f);
    }
    __syncthreads();
    for (int idx = tid; idx < TT * DD; idx += 256) {
        int t = idx / DD, d = idx % DD;
        const float* pp = hpart + ((size_t)(b * TT + t) * 8) * DD + d;
        float s = 0.f;
#pragma unroll
        for (int k = 0; k < 8; ++k) s += pp[k * DD];
        hm[t][d] = s * invc[t];
    }
    __syncthreads();
    for (int p = tid; p < TT * TT; p += 256) {
        int t = p / TT, u = p % TT;
        float s = 0.f;
        for (int d = 0; d < DD; ++d) s += hm[t][d] * hm[u][d];
        mb[t][u] = s;
    }
    __syncthreads();
    if (tid < TT) {
        float mx = -FLT_MAX;
        for (int u = 0; u < TT; ++u) mx = fmaxf(mx, mb[tid][u]);
        float e[TT]; float sum = 0.f;
        for (int u = 0; u < TT; ++u) { e[u] = __expf(mb[tid][u] - mx); sum += e[u]; }
        float inv = 1.f / sum;
        for (int u = 0; u < TT; ++u)
            beta[((size_t)b * TT + tid) * TT + u] = e[u] * inv;
    }
}

// ---------- K3: out = (h + h_temporal) * mask ----------
__global__ __launch_bounds__(256) void ktemporal(const float* __restrict__ h,
                                                 const float* __restrict__ beta,
                                                 const int* __restrict__ mask,
                                                 float* __restrict__ out) {
    int b = blockIdx.x >> 6;
    int q = (blockIdx.x & 63) * 256 + threadIdx.x;   // 0..16383 float2 slots
    int n = q >> 5;
    __shared__ float cf[TT][TT];
    for (int idx = threadIdx.x; idx < TT * TT; idx += 256) {
        int t = idx / TT, u = idx % TT;
        cf[t][u] = beta[((size_t)b * TT + t) * TT + u] + (t == u ? 1.f : 0.f);
    }
    __syncthreads();
    const float2* hp = (const float2*)h + (size_t)b * TT * 16384;
    float2* op = (float2*)out + (size_t)b * TT * 16384;
    const int* mp = mask + (size_t)b * TT * NN;
    float2 hv[TT];
#pragma unroll
    for (int u = 0; u < TT; ++u) hv[u] = hp[(size_t)u * 16384 + q];
    float2 z = {0.f, 0.f};
#pragma unroll
    for (int t = 0; t < TT; ++t) {
        float2 a = z;
#pragma unroll
        for (int u = 0; u < TT; ++u) {
            float c = cf[t][u];
            a.x += c * hv[u].x; a.y += c * hv[u].y;
        }
        int m = mp[(size_t)t * NN + n];
        op[(size_t)t * 16384 + q] = m ? a : z;
    }
}

// ---------- K4: spatial attention, MFMA, ht staged in LDS (kills 16x L2 amplification) ----------
// p = exp(adj_ij + 2 vi.vj - |vj|^2); per-row constants cancel in softmax.
// 4 waves; wave owns 16 rows x full 512 j (16 K-iters). No jh split, no exchange.
__global__ __launch_bounds__(256) void kspatial(const float* __restrict__ adj,
                                                const float* __restrict__ vel,
                                                const int* __restrict__ cnt,
                                                const int* __restrict__ rows,
                                                const float4* __restrict__ colinfo,
                                                const __bf16* __restrict__ ht,
                                                float* __restrict__ out) {
    int bx = blockIdx.x;
    int x = bx & 7;
    int m8 = bx >> 3;                  // 0..159
    int bt = x * 20 + (m8 >> 3);
    int i0 = (m8 & 7) * 64;
    int n_act = cnt[bt];
    if (i0 >= n_act) return;

    int tid = threadIdx.x;
    int w = tid >> 6, lane = tid & 63;  // w = row-group 0..3
    int arow = lane & 15;               // A row / C col index
    int kg = lane >> 4;                 // k-group 0..3

    __shared__ __bf16 hs[64][520];      // [d][j] bf16 tile; stride 260 dwords -> banks tile evenly
    __shared__ float4 ci[NN];

    for (int idx = tid; idx < NN; idx += 256)
        ci[idx] = colinfo[(size_t)bt * NN + idx];

    // stage ht tile: 64 rows x 512 bf16 = 64KB, read once. 16-BYTE copies (uint4).
    const ushort* htb = (const ushort*)(ht + (size_t)bt * DD * NN);
#pragma unroll
    for (int it = 0; it < 16; ++it) {
        int chunk = it * 256 + tid;     // 0..4095 16B-chunks
        int r = chunk >> 6;             // d-row (64 chunks/row)
        int cc = chunk & 63;
        *(uint4*)(&hs[r][cc * 8]) = *(const uint4*)(htb + (size_t)r * NN + cc * 8);
    }

    int slot = i0 + w * 16 + arow;
    int slotc = slot < n_act ? slot : n_act - 1;
    int row = rows[(size_t)bt * NN + slotc];
    float2 rv = ((const float2*)vel)[(size_t)bt * NN + row];
    float vx2 = 2.f * rv.x, vy2 = 2.f * rv.y;

    const float* arowp = adj + ((size_t)bt * NN + row) * NN;

    f32x4 zero = {0.f, 0.f, 0.f, 0.f};
    f32x4 acc[4];
#pragma unroll
    for (int nt = 0; nt < 4; ++nt) acc[nt] = zero;
    float lsum = 0.f;
    __syncthreads();

    // 2-deep adjacency prefetch, fully unrolled over 16 iters
    f32x4 a01[16], a23[16];
    {
        const f32x4* p0 = (const f32x4*)(arowp + kg * 8);
        a01[0] = __builtin_nontemporal_load(p0);
        a23[0] = __builtin_nontemporal_load(p0 + 1);
        a01[1] = __builtin_nontemporal_load(p0 + 8);
        a23[1] = __builtin_nontemporal_load(p0 + 9);
    }
#pragma unroll
    for (int c = 0; c < 16; ++c) {
        if (c < 14) {
            const f32x4* pn = (const f32x4*)(arowp + kg * 8 + (c + 2) * 32);
            a01[c + 2] = __builtin_nontemporal_load(pn);
            a23[c + 2] = __builtin_nontemporal_load(pn + 1);
        }
        int jb = kg * 8 + c * 32;
        const float4* ccp = &ci[jb];
        float p[8];
#pragma unroll
        for (int e = 0; e < 8; ++e) {
            float av = (e < 4) ? a01[c][e] : a23[c][e - 4];
            float4 cc = ccp[e];
            float l = av + cc.z + vx2 * cc.x + vy2 * cc.y;
            p[e] = __expf(l);
        }
        lsum += ((p[0] + p[1]) + (p[2] + p[3])) + ((p[4] + p[5]) + (p[6] + p[7]));
        bf16x8 af;
#pragma unroll
        for (int e = 0; e < 8; ++e) af[e] = (__bf16)p[e];
#pragma unroll
        for (int nt = 0; nt < 4; ++nt) {
            bf16x8 bf = *(const bf16x8*)(&hs[nt * 16 + arow][jb]);
            acc[nt] = __builtin_amdgcn_mfma_f32_16x16x32_bf16(af, bf, acc[nt], 0, 0, 0);
        }
    }

    lsum += __shfl_xor(lsum, 16, 64);
    lsum += __shfl_xor(lsum, 32, 64);
    float inv = 1.0f / fmaxf(lsum, 1e-8f);

    float* op = out + (size_t)bt * NN * DD;
#pragma unroll
    for (int q = 0; q < 4; ++q) {
        int cr = kg * 4 + q;
        int s2 = i0 + w * 16 + cr;
        int r2 = __shfl(row, cr, 64);
        float iv = __shfl(inv, cr, 64);
        if (s2 < n_act) {
#pragma unroll
            for (int nt = 0; nt < 4; ++nt) {
                size_t o = (size_t)r2 * DD + nt * 16 + arow;
                op[o] = op[o] + acc[nt][q] * iv;
            }
        }
    }
}

extern "C" void kernel_launch(void* const* d_in, const int* in_sizes, int n_in,
                              void* d_out, int out_size, void* d_ws, size_t ws_size,
                              hipStream_t stream) {
    const float* h   = (const float*)d_in[0];
    const float* vel = (const float*)d_in[1];
    const float* adj = (const float*)d_in[2];
    const int* mask  = (const int*)d_in[3];
    float* out = (float*)d_out;

    char* ws = (char*)d_ws;
    __bf16* ht      = (__bf16*)ws;                       ws += (size_t)BT * DD * NN * 2;
    float4* colinfo = (float4*)ws;                       ws += (size_t)BT * NN * 16;
    float* hpart    = (float*)ws;                        ws += (size_t)BT * 8 * DD * 4;
    int* cpart      = (int*)ws;                          ws += (size_t)BT * 8 * 4;
    float* beta     = (float*)ws;                        ws += (size_t)BB * TT * TT * 4;
    int* rows       = (int*)ws;                          ws += (size_t)BT * NN * 4;
    int* cnt        = (int*)ws;

    (void)hipMemsetAsync(cnt, 0, BT * sizeof(int), stream);
    kpre<<<BT * 8, 256, 0, stream>>>(h, vel, mask, ht, hpart, cpart, colinfo, rows, cnt);
    kbeta<<<BB, 256, 0, stream>>>(hpart, cpart, beta);
    ktemporal<<<BB * 64, 256, 0, stream>>>(h, beta, mask, out);
    kspatial<<<BT * 8, 256, 0, stream>>>(adj, vel, cnt, rows, colinfo, ht, out);
}

// Round 10
// 64.966 us; speedup vs baseline: 1.8304x; 1.0902x over previous
//
#include <hip/hip_runtime.h>
#include <float.h>

#define BB 8
#define TT 20
#define NN 512
#define DD 64
#define BT (BB*TT)

typedef __bf16 bf16x8 __attribute__((ext_vector_type(8)));
typedef float f32x4 __attribute__((ext_vector_type(4)));

// ---------- K1: per-slice transpose + partial mean + colinfo + per-slice compaction ----------
// rows stored per-slice (no cross-block atomic, no memset needed).
__global__ __launch_bounds__(256) void kpre(const float* __restrict__ h,
                                            const float* __restrict__ vel,
                                            const int* __restrict__ mask,
                                            __bf16* __restrict__ ht,
                                            float* __restrict__ hpart,
                                            int* __restrict__ cpart,
                                            float4* __restrict__ colinfo,
                                            int* __restrict__ rows) {
    int bx = blockIdx.x;
    int bt = bx >> 3, slice = bx & 7;
    int n0 = slice * 64;
    int tid = threadIdx.x;
    const float* hp = h + ((size_t)bt * NN + n0) * DD;
    const int* mp = mask + (size_t)bt * NN + n0;
    short* htp = (short*)(ht + (size_t)bt * DD * NN) + n0;

    __shared__ __bf16 t[64][72];
    __shared__ float sred[16][64];

    int d4 = (tid & 15) << 2;
    int nl0 = tid >> 4;
    float s0 = 0.f, s1 = 0.f, s2 = 0.f, s3 = 0.f;
#pragma unroll
    for (int it = 0; it < 4; ++it) {
        int nl = it * 16 + nl0;
        float4 v = *(const float4*)(hp + (size_t)nl * DD + d4);
        if (mp[nl]) { s0 += v.x; s1 += v.y; s2 += v.z; s3 += v.w; }
        t[d4 + 0][nl] = (__bf16)v.x;
        t[d4 + 1][nl] = (__bf16)v.y;
        t[d4 + 2][nl] = (__bf16)v.z;
        t[d4 + 3][nl] = (__bf16)v.w;
    }
    int g = tid >> 4;
    sred[g][d4 + 0] = s0; sred[g][d4 + 1] = s1;
    sred[g][d4 + 2] = s2; sred[g][d4 + 3] = s3;
    __syncthreads();
#pragma unroll
    for (int it = 0; it < 4; ++it) {
        int idx = it * 256 + tid;
        int d = idx >> 4, s = idx & 15;
        short4 v4 = *(const short4*)&t[d][4 * s];
        *(short4*)(htp + (size_t)d * NN + 4 * s) = v4;
    }
    if (tid < 64) {
        float tot = 0.f;
#pragma unroll
        for (int k = 0; k < 16; ++k) tot += sred[k][tid];
        hpart[(size_t)bx * DD + tid] = tot;
    }
    if (tid < 64) {                       // wave 0: colinfo + per-slice compaction
        int j = n0 + tid;
        float2 v = ((const float2*)vel)[(size_t)bt * NN + j];
        int m = mp[tid];
        float cz = m ? -(v.x * v.x + v.y * v.y) : -3e38f;
        colinfo[(size_t)bt * NN + j] = make_float4(v.x, v.y, cz, 0.f);
        unsigned long long bal = __ballot(m != 0);
        int pos = __popcll(bal & ((1ull << tid) - 1ull));
        if (tid == 0) cpart[bx] = __popcll(bal);
        if (m) rows[(size_t)bt * NN + n0 + pos] = j;
    }
}

// ---------- K2: inline beta (hmean finalize + Gram + softmax) + temporal pass ----------
__global__ __launch_bounds__(256) void ktempbeta(const float* __restrict__ h,
                                                 const int* __restrict__ mask,
                                                 const float* __restrict__ hpart,
                                                 const int* __restrict__ cpart,
                                                 float* __restrict__ out) {
    int b = blockIdx.x >> 6;
    int q = (blockIdx.x & 63) * 256 + threadIdx.x;   // 0..16383 float2 slots
    int n = q >> 5;
    int tid = threadIdx.x;
    __shared__ float hm[TT][DD];
    __shared__ float mbuf[TT][TT];
    __shared__ float cf[TT][TT];
    __shared__ float invc[TT];
    if (tid < TT) {
        int c = 0;
#pragma unroll
        for (int k = 0; k < 8; ++k) c += cpart[(b * TT + tid) * 8 + k];
        invc[tid] = 1.f / fmaxf((float)c, 1.f);
    }
    __syncthreads();
    for (int idx = tid; idx < TT * DD; idx += 256) {
        int t = idx >> 6, d = idx & 63;
        const float* pp = hpart + ((size_t)(b * TT + t) * 8) * DD + d;
        float s = 0.f;
#pragma unroll
        for (int k = 0; k < 8; ++k) s += pp[k * DD];
        hm[t][d] = s * invc[t];
    }
    __syncthreads();
    for (int p = tid; p < TT * TT; p += 256) {
        int t = p / TT, u = p % TT;
        float s = 0.f;
        for (int d = 0; d < DD; ++d) s += hm[t][d] * hm[u][d];
        mbuf[t][u] = s;
    }
    __syncthreads();
    if (tid < TT) {
        float mx = -FLT_MAX;
        for (int u = 0; u < TT; ++u) mx = fmaxf(mx, mbuf[tid][u]);
        float e[TT]; float sum = 0.f;
        for (int u = 0; u < TT; ++u) { e[u] = __expf(mbuf[tid][u] - mx); sum += e[u]; }
        float inv = 1.f / sum;
        for (int u = 0; u < TT; ++u)
            cf[tid][u] = e[u] * inv + (tid == u ? 1.f : 0.f);
    }
    __syncthreads();
    const float2* hp = (const float2*)h + (size_t)b * TT * 16384;
    float2* op = (float2*)out + (size_t)b * TT * 16384;
    const int* mp = mask + (size_t)b * TT * NN;
    float2 hv[TT];
#pragma unroll
    for (int u = 0; u < TT; ++u) hv[u] = hp[(size_t)u * 16384 + q];
    float2 z = {0.f, 0.f};
#pragma unroll
    for (int t = 0; t < TT; ++t) {
        float2 a = z;
#pragma unroll
        for (int u = 0; u < TT; ++u) {
            float c = cf[t][u];
            a.x += c * hv[u].x; a.y += c * hv[u].y;
        }
        int m = mp[(size_t)t * NN + n];
        op[(size_t)t * 16384 + q] = m ? a : z;
    }
}

// ---------- K3: spatial attention, MFMA, LDS-staged ht, prefix row lookup ----------
__global__ __launch_bounds__(256) void kspatial(const float* __restrict__ adj,
                                                const float* __restrict__ vel,
                                                const int* __restrict__ cpart,
                                                const int* __restrict__ rows,
                                                const float4* __restrict__ colinfo,
                                                const __bf16* __restrict__ ht,
                                                float* __restrict__ out) {
    int bx = blockIdx.x;
    int x = bx & 7;
    int m8 = bx >> 3;                  // 0..159
    int bt = x * 20 + (m8 >> 3);
    int i0 = (m8 & 7) * 64;

    const int* cp = cpart + bt * 8;
    int cs[8];
#pragma unroll
    for (int s = 0; s < 8; ++s) cs[s] = cp[s];
    int n_act = 0;
#pragma unroll
    for (int s = 0; s < 8; ++s) n_act += cs[s];
    if (i0 >= n_act) return;

    int tid = threadIdx.x;
    int w = tid >> 6, lane = tid & 63;  // w = row-group 0..3
    int arow = lane & 15;               // A row / C col index
    int kg = lane >> 4;                 // k-group 0..3

    __shared__ __bf16 hs[64][520];
    __shared__ float4 ci[NN];

    for (int idx = tid; idx < NN; idx += 256)
        ci[idx] = colinfo[(size_t)bt * NN + idx];

    const ushort* htb = (const ushort*)(ht + (size_t)bt * DD * NN);
#pragma unroll
    for (int it = 0; it < 16; ++it) {
        int chunk = it * 256 + tid;
        int r = chunk >> 6;
        int cc = chunk & 63;
        *(uint4*)(&hs[r][cc * 8]) = *(const uint4*)(htb + (size_t)r * NN + cc * 8);
    }

    int slot = i0 + w * 16 + arow;
    int slotc = slot < n_act ? slot : n_act - 1;
    int row = 0, base = 0;
#pragma unroll
    for (int s = 0; s < 8; ++s) {
        if (slotc >= base && slotc < base + cs[s])
            row = rows[(size_t)bt * NN + s * 64 + (slotc - base)];
        base += cs[s];
    }
    float2 rv = ((const float2*)vel)[(size_t)bt * NN + row];
    float vx2 = 2.f * rv.x, vy2 = 2.f * rv.y;

    const float* arowp = adj + ((size_t)bt * NN + row) * NN;

    f32x4 zero = {0.f, 0.f, 0.f, 0.f};
    f32x4 acc[4];
#pragma unroll
    for (int nt = 0; nt < 4; ++nt) acc[nt] = zero;
    float lsum = 0.f;
    __syncthreads();

    f32x4 a01[16], a23[16];
    {
        const f32x4* p0 = (const f32x4*)(arowp + kg * 8);
        a01[0] = __builtin_nontemporal_load(p0);
        a23[0] = __builtin_nontemporal_load(p0 + 1);
        a01[1] = __builtin_nontemporal_load(p0 + 8);
        a23[1] = __builtin_nontemporal_load(p0 + 9);
    }
#pragma unroll
    for (int c = 0; c < 16; ++c) {
        if (c < 14) {
            const f32x4* pn = (const f32x4*)(arowp + kg * 8 + (c + 2) * 32);
            a01[c + 2] = __builtin_nontemporal_load(pn);
            a23[c + 2] = __builtin_nontemporal_load(pn + 1);
        }
        int jb = kg * 8 + c * 32;
        const float4* ccp = &ci[jb];
        float p[8];
#pragma unroll
        for (int e = 0; e < 8; ++e) {
            float av = (e < 4) ? a01[c][e] : a23[c][e - 4];
            float4 cc = ccp[e];
            float l = av + cc.z + vx2 * cc.x + vy2 * cc.y;
            p[e] = __expf(l);
        }
        lsum += ((p[0] + p[1]) + (p[2] + p[3])) + ((p[4] + p[5]) + (p[6] + p[7]));
        bf16x8 af;
#pragma unroll
        for (int e = 0; e < 8; ++e) af[e] = (__bf16)p[e];
#pragma unroll
        for (int nt = 0; nt < 4; ++nt) {
            bf16x8 bf = *(const bf16x8*)(&hs[nt * 16 + arow][jb]);
            acc[nt] = __builtin_amdgcn_mfma_f32_16x16x32_bf16(af, bf, acc[nt], 0, 0, 0);
        }
    }

    lsum += __shfl_xor(lsum, 16, 64);
    lsum += __shfl_xor(lsum, 32, 64);
    float inv = 1.0f / fmaxf(lsum, 1e-8f);

    float* op = out + (size_t)bt * NN * DD;
#pragma unroll
    for (int q = 0; q < 4; ++q) {
        int cr = kg * 4 + q;
        int s2 = i0 + w * 16 + cr;
        int r2 = __shfl(row, cr, 64);
        float iv = __shfl(inv, cr, 64);
        if (s2 < n_act) {
#pragma unroll
            for (int nt = 0; nt < 4; ++nt) {
                size_t o = (size_t)r2 * DD + nt * 16 + arow;
                op[o] = op[o] + acc[nt][q] * iv;
            }
        }
    }
}

extern "C" void kernel_launch(void* const* d_in, const int* in_sizes, int n_in,
                              void* d_out, int out_size, void* d_ws, size_t ws_size,
                              hipStream_t stream) {
    const float* h   = (const float*)d_in[0];
    const float* vel = (const float*)d_in[1];
    const float* adj = (const float*)d_in[2];
    const int* mask  = (const int*)d_in[3];
    float* out = (float*)d_out;

    char* ws = (char*)d_ws;
    __bf16* ht      = (__bf16*)ws;                       ws += (size_t)BT * DD * NN * 2;
    float4* colinfo = (float4*)ws;                       ws += (size_t)BT * NN * 16;
    float* hpart    = (float*)ws;                        ws += (size_t)BT * 8 * DD * 4;
    int* cpart      = (int*)ws;                          ws += (size_t)BT * 8 * 4;
    int* rows       = (int*)ws;

    kpre<<<BT * 8, 256, 0, stream>>>(h, vel, mask, ht, hpart, cpart, colinfo, rows);
    ktempbeta<<<BB * 64, 256, 0, stream>>>(h, mask, hpart, cpart, out);
    kspatial<<<BT * 8, 256, 0, stream>>>(adj, vel, cpart, rows, colinfo, ht, out);
}

// Round 11
// 63.193 us; speedup vs baseline: 1.8817x; 1.0281x over previous
//
#include <hip/hip_runtime.h>
#include <float.h>

#define BB 8
#define TT 20
#define NN 512
#define DD 64
#define BT (BB*TT)

typedef __bf16 bf16x8 __attribute__((ext_vector_type(8)));
typedef __bf16 bf16x4 __attribute__((ext_vector_type(4)));
typedef float f32x4 __attribute__((ext_vector_type(4)));

// ---------- K1: transpose->ht + bf16 copy->hb16 + partial mean + colinfo + compaction ----------
__global__ __launch_bounds__(256) void kpre(const float* __restrict__ h,
                                            const float* __restrict__ vel,
                                            const int* __restrict__ mask,
                                            __bf16* __restrict__ ht,
                                            __bf16* __restrict__ hb16,
                                            float* __restrict__ hpart,
                                            int* __restrict__ cpart,
                                            float4* __restrict__ colinfo,
                                            int* __restrict__ rows) {
    int bx = blockIdx.x;
    int bt = bx >> 3, slice = bx & 7;
    int n0 = slice * 64;
    int tid = threadIdx.x;
    const float* hp = h + ((size_t)bt * NN + n0) * DD;
    const int* mp = mask + (size_t)bt * NN + n0;
    short* htp = (short*)(ht + (size_t)bt * DD * NN) + n0;

    __shared__ __bf16 t[64][72];
    __shared__ float sred[16][64];

    int d4 = (tid & 15) << 2;
    int nl0 = tid >> 4;
    float s0 = 0.f, s1 = 0.f, s2 = 0.f, s3 = 0.f;
#pragma unroll
    for (int it = 0; it < 4; ++it) {
        int nl = it * 16 + nl0;
        float4 v = *(const float4*)(hp + (size_t)nl * DD + d4);
        if (mp[nl]) { s0 += v.x; s1 += v.y; s2 += v.z; s3 += v.w; }
        __bf16 b0 = (__bf16)v.x, b1 = (__bf16)v.y, b2 = (__bf16)v.z, b3 = (__bf16)v.w;
        t[d4 + 0][nl] = b0;
        t[d4 + 1][nl] = b1;
        t[d4 + 2][nl] = b2;
        t[d4 + 3][nl] = b3;
        bf16x4 pv = {b0, b1, b2, b3};
        *(bf16x4*)(hb16 + ((size_t)bt * NN + n0 + nl) * DD + d4) = pv;
    }
    int g = tid >> 4;
    sred[g][d4 + 0] = s0; sred[g][d4 + 1] = s1;
    sred[g][d4 + 2] = s2; sred[g][d4 + 3] = s3;
    __syncthreads();
#pragma unroll
    for (int it = 0; it < 4; ++it) {
        int idx = it * 256 + tid;
        int d = idx >> 4, s = idx & 15;
        short4 v4 = *(const short4*)&t[d][4 * s];
        *(short4*)(htp + (size_t)d * NN + 4 * s) = v4;
    }
    if (tid < 64) {
        float tot = 0.f;
#pragma unroll
        for (int k = 0; k < 16; ++k) tot += sred[k][tid];
        hpart[(size_t)bx * DD + tid] = tot;
    }
    if (tid < 64) {                       // wave 0: colinfo + per-slice compaction
        int j = n0 + tid;
        float2 v = ((const float2*)vel)[(size_t)bt * NN + j];
        int m = mp[tid];
        float cz = m ? -(v.x * v.x + v.y * v.y) : -3e38f;
        colinfo[(size_t)bt * NN + j] = make_float4(v.x, v.y, cz, 0.f);
        unsigned long long bal = __ballot(m != 0);
        int pos = __popcll(bal & ((1ull << tid) - 1ull));
        if (tid == 0) cpart[bx] = __popcll(bal);
        if (m) rows[(size_t)bt * NN + n0 + pos] = j;
    }
}

// ---------- K2: inline beta + temporal pass, reading bf16 h copy ----------
// grid BB*32 blocks; thread owns one bf16x4 group (4 d of one node) across all t,u.
__global__ __launch_bounds__(256) void ktempbeta(const __bf16* __restrict__ hb16,
                                                 const int* __restrict__ mask,
                                                 const float* __restrict__ hpart,
                                                 const int* __restrict__ cpart,
                                                 float* __restrict__ out) {
    int b = blockIdx.x >> 5;
    int q4 = (blockIdx.x & 31) * 256 + threadIdx.x;  // 0..8191 bf16x4 groups
    int n = q4 >> 4;
    int tid = threadIdx.x;
    __shared__ float hm[TT][DD];
    __shared__ float mbuf[TT][TT];
    __shared__ float cf[TT][TT];
    __shared__ float invc[TT];
    if (tid < TT) {
        int c = 0;
#pragma unroll
        for (int k = 0; k < 8; ++k) c += cpart[(b * TT + tid) * 8 + k];
        invc[tid] = 1.f / fmaxf((float)c, 1.f);
    }
    __syncthreads();
    for (int idx = tid; idx < TT * DD; idx += 256) {
        int t = idx >> 6, d = idx & 63;
        const float* pp = hpart + ((size_t)(b * TT + t) * 8) * DD + d;
        float s = 0.f;
#pragma unroll
        for (int k = 0; k < 8; ++k) s += pp[k * DD];
        hm[t][d] = s * invc[t];
    }
    __syncthreads();
    for (int p = tid; p < TT * TT; p += 256) {
        int t = p / TT, u = p % TT;
        float s = 0.f;
        for (int d = 0; d < DD; ++d) s += hm[t][d] * hm[u][d];
        mbuf[t][u] = s;
    }
    __syncthreads();
    if (tid < TT) {
        float mx = -FLT_MAX;
        for (int u = 0; u < TT; ++u) mx = fmaxf(mx, mbuf[tid][u]);
        float e[TT]; float sum = 0.f;
        for (int u = 0; u < TT; ++u) { e[u] = __expf(mbuf[tid][u] - mx); sum += e[u]; }
        float inv = 1.f / sum;
        for (int u = 0; u < TT; ++u)
            cf[tid][u] = e[u] * inv + (tid == u ? 1.f : 0.f);
    }
    __syncthreads();
    const bf16x4* hp = (const bf16x4*)hb16 + (size_t)b * TT * 8192;
    float4* op = (float4*)out + (size_t)b * TT * 8192;
    const int* mp = mask + (size_t)b * TT * NN;
    float4 hv[TT];
#pragma unroll
    for (int u = 0; u < TT; ++u) {
        bf16x4 x = hp[(size_t)u * 8192 + q4];
        hv[u].x = (float)x[0]; hv[u].y = (float)x[1];
        hv[u].z = (float)x[2]; hv[u].w = (float)x[3];
    }
    float4 z = {0.f, 0.f, 0.f, 0.f};
#pragma unroll
    for (int t = 0; t < TT; ++t) {
        float4 a = z;
#pragma unroll
        for (int u = 0; u < TT; ++u) {
            float c = cf[t][u];
            a.x += c * hv[u].x; a.y += c * hv[u].y;
            a.z += c * hv[u].z; a.w += c * hv[u].w;
        }
        int m = mp[(size_t)t * NN + n];
        op[(size_t)t * 8192 + q4] = m ? a : z;
    }
}

// ---------- K3: spatial attention, MFMA, LDS-staged ht (plain loads -> L3 retention) ----------
__global__ __launch_bounds__(256) void kspatial(const float* __restrict__ adj,
                                                const float* __restrict__ vel,
                                                const int* __restrict__ cpart,
                                                const int* __restrict__ rows,
                                                const float4* __restrict__ colinfo,
                                                const __bf16* __restrict__ ht,
                                                float* __restrict__ out) {
    int bx = blockIdx.x;
    int x = bx & 7;
    int m8 = bx >> 3;                  // 0..159
    int bt = x * 20 + (m8 >> 3);
    int i0 = (m8 & 7) * 64;

    const int* cp = cpart + bt * 8;
    int cs[8];
#pragma unroll
    for (int s = 0; s < 8; ++s) cs[s] = cp[s];
    int n_act = 0;
#pragma unroll
    for (int s = 0; s < 8; ++s) n_act += cs[s];
    if (i0 >= n_act) return;

    int tid = threadIdx.x;
    int w = tid >> 6, lane = tid & 63;  // w = row-group 0..3
    int arow = lane & 15;               // A row / C col index
    int kg = lane >> 4;                 // k-group 0..3

    __shared__ __bf16 hs[64][520];
    __shared__ float4 ci[NN];

    for (int idx = tid; idx < NN; idx += 256)
        ci[idx] = colinfo[(size_t)bt * NN + idx];

    const ushort* htb = (const ushort*)(ht + (size_t)bt * DD * NN);
#pragma unroll
    for (int it = 0; it < 16; ++it) {
        int chunk = it * 256 + tid;
        int r = chunk >> 6;
        int cc = chunk & 63;
        *(uint4*)(&hs[r][cc * 8]) = *(const uint4*)(htb + (size_t)r * NN + cc * 8);
    }

    int slot = i0 + w * 16 + arow;
    int slotc = slot < n_act ? slot : n_act - 1;
    int row = 0, base = 0;
#pragma unroll
    for (int s = 0; s < 8; ++s) {
        if (slotc >= base && slotc < base + cs[s])
            row = rows[(size_t)bt * NN + s * 64 + (slotc - base)];
        base += cs[s];
    }
    float2 rv = ((const float2*)vel)[(size_t)bt * NN + row];
    float vx2 = 2.f * rv.x, vy2 = 2.f * rv.y;

    const float* arowp = adj + ((size_t)bt * NN + row) * NN;

    f32x4 zero = {0.f, 0.f, 0.f, 0.f};
    f32x4 acc[4];
#pragma unroll
    for (int nt = 0; nt < 4; ++nt) acc[nt] = zero;
    float lsum = 0.f;
    __syncthreads();

    f32x4 a01[16], a23[16];
    {
        const f32x4* p0 = (const f32x4*)(arowp + kg * 8);
        a01[0] = p0[0];
        a23[0] = p0[1];
        a01[1] = p0[8];
        a23[1] = p0[9];
    }
#pragma unroll
    for (int c = 0; c < 16; ++c) {
        if (c < 14) {
            const f32x4* pn = (const f32x4*)(arowp + kg * 8 + (c + 2) * 32);
            a01[c + 2] = pn[0];
            a23[c + 2] = pn[1];
        }
        int jb = kg * 8 + c * 32;
        const float4* ccp = &ci[jb];
        float p[8];
#pragma unroll
        for (int e = 0; e < 8; ++e) {
            float av = (e < 4) ? a01[c][e] : a23[c][e - 4];
            float4 cc = ccp[e];
            float l = av + cc.z + vx2 * cc.x + vy2 * cc.y;
            p[e] = __expf(l);
        }
        lsum += ((p[0] + p[1]) + (p[2] + p[3])) + ((p[4] + p[5]) + (p[6] + p[7]));
        bf16x8 af;
#pragma unroll
        for (int e = 0; e < 8; ++e) af[e] = (__bf16)p[e];
#pragma unroll
        for (int nt = 0; nt < 4; ++nt) {
            bf16x8 bf = *(const bf16x8*)(&hs[nt * 16 + arow][jb]);
            acc[nt] = __builtin_amdgcn_mfma_f32_16x16x32_bf16(af, bf, acc[nt], 0, 0, 0);
        }
    }

    lsum += __shfl_xor(lsum, 16, 64);
    lsum += __shfl_xor(lsum, 32, 64);
    float inv = 1.0f / fmaxf(lsum, 1e-8f);

    float* op = out + (size_t)bt * NN * DD;
#pragma unroll
    for (int q = 0; q < 4; ++q) {
        int cr = kg * 4 + q;
        int s2 = i0 + w * 16 + cr;
        int r2 = __shfl(row, cr, 64);
        float iv = __shfl(inv, cr, 64);
        if (s2 < n_act) {
#pragma unroll
            for (int nt = 0; nt < 4; ++nt) {
                size_t o = (size_t)r2 * DD + nt * 16 + arow;
                op[o] = op[o] + acc[nt][q] * iv;
            }
        }
    }
}

extern "C" void kernel_launch(void* const* d_in, const int* in_sizes, int n_in,
                              void* d_out, int out_size, void* d_ws, size_t ws_size,
                              hipStream_t stream) {
    const float* h   = (const float*)d_in[0];
    const float* vel = (const float*)d_in[1];
    const float* adj = (const float*)d_in[2];
    const int* mask  = (const int*)d_in[3];
    float* out = (float*)d_out;

    char* ws = (char*)d_ws;
    __bf16* ht      = (__bf16*)ws;                       ws += (size_t)BT * DD * NN * 2;
    __bf16* hb16    = (__bf16*)ws;                       ws += (size_t)BT * NN * DD * 2;
    float4* colinfo = (float4*)ws;                       ws += (size_t)BT * NN * 16;
    float* hpart    = (float*)ws;                        ws += (size_t)BT * 8 * DD * 4;
    int* cpart      = (int*)ws;                          ws += (size_t)BT * 8 * 4;
    int* rows       = (int*)ws;

    kpre<<<BT * 8, 256, 0, stream>>>(h, vel, mask, ht, hb16, hpart, cpart, colinfo, rows);
    ktempbeta<<<BB * 32, 256, 0, stream>>>(hb16, mask, hpart, cpart, out);
    kspatial<<<BT * 8, 256, 0, stream>>>(adj, vel, cpart, rows, colinfo, ht, out);
}

// Round 12
// 57.106 us; speedup vs baseline: 2.0823x; 1.1066x over previous
//
#include <hip/hip_runtime.h>
#include <float.h>

#define BB 8
#define TT 20
#define NN 512
#define DD 64
#define BT (BB*TT)

typedef __bf16 bf16x8 __attribute__((ext_vector_type(8)));
typedef __bf16 bf16x4 __attribute__((ext_vector_type(4)));
typedef float f32x4 __attribute__((ext_vector_type(4)));

// ---------- K1: transpose->ht + bf16 copy->hb16 + partial mean + colinfo(f2) + compaction ----------
__global__ __launch_bounds__(256) void kpre(const float* __restrict__ h,
                                            const float* __restrict__ vel,
                                            const int* __restrict__ mask,
                                            __bf16* __restrict__ ht,
                                            __bf16* __restrict__ hb16,
                                            float* __restrict__ hpart,
                                            int* __restrict__ cpart,
                                            float2* __restrict__ colinfo,
                                            int* __restrict__ rows) {
    int bx = blockIdx.x;
    int bt = bx >> 3, slice = bx & 7;
    int n0 = slice * 64;
    int tid = threadIdx.x;
    const float* hp = h + ((size_t)bt * NN + n0) * DD;
    const int* mp = mask + (size_t)bt * NN + n0;
    short* htp = (short*)(ht + (size_t)bt * DD * NN) + n0;

    __shared__ __bf16 t[64][72];
    __shared__ float sred[16][64];

    int d4 = (tid & 15) << 2;
    int nl0 = tid >> 4;
    float s0 = 0.f, s1 = 0.f, s2 = 0.f, s3 = 0.f;
#pragma unroll
    for (int it = 0; it < 4; ++it) {
        int nl = it * 16 + nl0;
        float4 v = *(const float4*)(hp + (size_t)nl * DD + d4);
        if (mp[nl]) { s0 += v.x; s1 += v.y; s2 += v.z; s3 += v.w; }
        __bf16 b0 = (__bf16)v.x, b1 = (__bf16)v.y, b2 = (__bf16)v.z, b3 = (__bf16)v.w;
        t[d4 + 0][nl] = b0;
        t[d4 + 1][nl] = b1;
        t[d4 + 2][nl] = b2;
        t[d4 + 3][nl] = b3;
        bf16x4 pv = {b0, b1, b2, b3};
        *(bf16x4*)(hb16 + ((size_t)bt * NN + n0 + nl) * DD + d4) = pv;
    }
    int g = tid >> 4;
    sred[g][d4 + 0] = s0; sred[g][d4 + 1] = s1;
    sred[g][d4 + 2] = s2; sred[g][d4 + 3] = s3;
    __syncthreads();
#pragma unroll
    for (int it = 0; it < 4; ++it) {
        int idx = it * 256 + tid;
        int d = idx >> 4, s = idx & 15;
        short4 v4 = *(const short4*)&t[d][4 * s];
        *(short4*)(htp + (size_t)d * NN + 4 * s) = v4;
    }
    if (tid < 64) {
        float tot = 0.f;
#pragma unroll
        for (int k = 0; k < 16; ++k) tot += sred[k][tid];
        hpart[(size_t)bx * DD + tid] = tot;
    }
    if (tid < 64) {                       // wave 0: colinfo + per-slice compaction
        int j = n0 + tid;
        float2 v = ((const float2*)vel)[(size_t)bt * NN + j];
        int m = mp[tid];
        float2 cw;
        cw.x = m ? v.x : 1e18f;
        cw.y = m ? v.y : 1e18f;           // masked -> logit ~ -2e36 -> exp = 0
        colinfo[(size_t)bt * NN + j] = cw;
        unsigned long long bal = __ballot(m != 0);
        int pos = __popcll(bal & ((1ull << tid) - 1ull));
        if (tid == 0) cpart[bx] = __popcll(bal);
        if (m) rows[(size_t)bt * NN + n0 + pos] = j;
    }
}

// ---------- K2: inline beta + temporal pass, reading bf16 h copy ----------
__global__ __launch_bounds__(256) void ktempbeta(const __bf16* __restrict__ hb16,
                                                 const int* __restrict__ mask,
                                                 const float* __restrict__ hpart,
                                                 const int* __restrict__ cpart,
                                                 float* __restrict__ out) {
    int b = blockIdx.x >> 5;
    int q4 = (blockIdx.x & 31) * 256 + threadIdx.x;  // 0..8191 bf16x4 groups
    int n = q4 >> 4;
    int tid = threadIdx.x;
    __shared__ float hm[TT][DD];
    __shared__ float mbuf[TT][TT];
    __shared__ float cf[TT][TT];
    __shared__ float invc[TT];
    if (tid < TT) {
        int c = 0;
#pragma unroll
        for (int k = 0; k < 8; ++k) c += cpart[(b * TT + tid) * 8 + k];
        invc[tid] = 1.f / fmaxf((float)c, 1.f);
    }
    __syncthreads();
    for (int idx = tid; idx < TT * DD; idx += 256) {
        int t = idx >> 6, d = idx & 63;
        const float* pp = hpart + ((size_t)(b * TT + t) * 8) * DD + d;
        float s = 0.f;
#pragma unroll
        for (int k = 0; k < 8; ++k) s += pp[k * DD];
        hm[t][d] = s * invc[t];
    }
    __syncthreads();
    for (int p = tid; p < TT * TT; p += 256) {
        int t = p / TT, u = p % TT;
        float s = 0.f;
        for (int d = 0; d < DD; ++d) s += hm[t][d] * hm[u][d];
        mbuf[t][u] = s;
    }
    __syncthreads();
    if (tid < TT) {
        float mx = -FLT_MAX;
        for (int u = 0; u < TT; ++u) mx = fmaxf(mx, mbuf[tid][u]);
        float e[TT]; float sum = 0.f;
        for (int u = 0; u < TT; ++u) { e[u] = __expf(mbuf[tid][u] - mx); sum += e[u]; }
        float inv = 1.f / sum;
        for (int u = 0; u < TT; ++u)
            cf[tid][u] = e[u] * inv + (tid == u ? 1.f : 0.f);
    }
    __syncthreads();
    const bf16x4* hp = (const bf16x4*)hb16 + (size_t)b * TT * 8192;
    float4* op = (float4*)out + (size_t)b * TT * 8192;
    const int* mp = mask + (size_t)b * TT * NN;
    float4 hv[TT];
#pragma unroll
    for (int u = 0; u < TT; ++u) {
        bf16x4 x = hp[(size_t)u * 8192 + q4];
        hv[u].x = (float)x[0]; hv[u].y = (float)x[1];
        hv[u].z = (float)x[2]; hv[u].w = (float)x[3];
    }
    float4 z = {0.f, 0.f, 0.f, 0.f};
#pragma unroll
    for (int t = 0; t < TT; ++t) {
        float4 a = z;
#pragma unroll
        for (int u = 0; u < TT; ++u) {
            float c = cf[t][u];
            a.x += c * hv[u].x; a.y += c * hv[u].y;
            a.z += c * hv[u].z; a.w += c * hv[u].w;
        }
        int m = mp[(size_t)t * NN + n];
        op[(size_t)t * 8192 + q4] = m ? a : z;
    }
}

// ---------- K3: spatial attention, MFMA, j-split LDS staging -> 4 blocks/CU ----------
__global__ __launch_bounds__(256, 4) void kspatial(const float* __restrict__ adj,
                                                   const float* __restrict__ vel,
                                                   const int* __restrict__ cpart,
                                                   const int* __restrict__ rows,
                                                   const float2* __restrict__ colinfo,
                                                   const __bf16* __restrict__ ht,
                                                   float* __restrict__ out) {
    int bx = blockIdx.x;
    int x = bx & 7;
    int m8 = bx >> 3;                  // 0..159
    int bt = x * 20 + (m8 >> 3);
    int i0 = (m8 & 7) * 64;

    const int* cp = cpart + bt * 8;
    int cs[8];
#pragma unroll
    for (int s = 0; s < 8; ++s) cs[s] = cp[s];
    int n_act = 0;
#pragma unroll
    for (int s = 0; s < 8; ++s) n_act += cs[s];
    if (i0 >= n_act) return;

    int tid = threadIdx.x;
    int w = tid >> 6, lane = tid & 63;  // w = row-group 0..3
    int arow = lane & 15;               // A row / C col index
    int kg = lane >> 4;                 // k-group 0..3

    __shared__ __bf16 hs[64][264];      // half-tile: 64 d x 256 j (+8 pad)
    __shared__ float2 vc[NN];           // 4KB velocity columns

    vc[tid] = colinfo[(size_t)bt * NN + tid];
    vc[256 + tid] = colinfo[(size_t)bt * NN + 256 + tid];

    int slot = i0 + w * 16 + arow;
    int slotc = slot < n_act ? slot : n_act - 1;
    int row = 0, base = 0;
#pragma unroll
    for (int s = 0; s < 8; ++s) {
        if (slotc >= base && slotc < base + cs[s])
            row = rows[(size_t)bt * NN + s * 64 + (slotc - base)];
        base += cs[s];
    }
    float2 rv = ((const float2*)vel)[(size_t)bt * NN + row];
    float vx2 = 2.f * rv.x, vy2 = 2.f * rv.y;

    const float* arowp = adj + ((size_t)bt * NN + row) * NN;
    const ushort* htb = (const ushort*)(ht + (size_t)bt * DD * NN);

    f32x4 zero = {0.f, 0.f, 0.f, 0.f};
    f32x4 acc[4];
#pragma unroll
    for (int nt = 0; nt < 4; ++nt) acc[nt] = zero;
    float lsum = 0.f;

#pragma unroll
    for (int half = 0; half < 2; ++half) {
        __syncthreads();                 // hs safe to overwrite; also covers vc on half 0
        const ushort* src = htb + half * 256;
#pragma unroll
        for (int it = 0; it < 8; ++it) {
            int chunk = it * 256 + tid;  // 0..2047 16B-chunks
            int r = chunk >> 5;          // d-row (32 chunks/row)
            int cc = chunk & 31;
            *(uint4*)(&hs[r][cc * 8]) = *(const uint4*)(src + (size_t)r * NN + cc * 8);
        }
        __syncthreads();

        const float* ap = arowp + half * 256;
        const float2* vcp = &vc[half * 256];
        f32x4 c01 = *(const f32x4*)(ap + kg * 8);
        f32x4 c23 = *(const f32x4*)(ap + kg * 8 + 4);
#pragma unroll
        for (int c = 0; c < 8; ++c) {
            f32x4 n01, n23;
            if (c < 7) {
                n01 = *(const f32x4*)(ap + kg * 8 + (c + 1) * 32);
                n23 = *(const f32x4*)(ap + kg * 8 + (c + 1) * 32 + 4);
            }
            int jb = kg * 8 + c * 32;
            float p[8];
#pragma unroll
            for (int e = 0; e < 8; ++e) {
                float av = (e < 4) ? c01[e] : c23[e - 4];
                float2 cc2 = vcp[jb + e];
                float l = av + cc2.x * (vx2 - cc2.x) + cc2.y * (vy2 - cc2.y);
                p[e] = __expf(l);
            }
            lsum += ((p[0] + p[1]) + (p[2] + p[3])) + ((p[4] + p[5]) + (p[6] + p[7]));
            bf16x8 af;
#pragma unroll
            for (int e = 0; e < 8; ++e) af[e] = (__bf16)p[e];
#pragma unroll
            for (int nt = 0; nt < 4; ++nt) {
                bf16x8 bf = *(const bf16x8*)(&hs[nt * 16 + arow][jb]);
                acc[nt] = __builtin_amdgcn_mfma_f32_16x16x32_bf16(af, bf, acc[nt], 0, 0, 0);
            }
            c01 = n01; c23 = n23;
        }
    }

    lsum += __shfl_xor(lsum, 16, 64);
    lsum += __shfl_xor(lsum, 32, 64);
    float inv = 1.0f / fmaxf(lsum, 1e-8f);

    float* op = out + (size_t)bt * NN * DD;
#pragma unroll
    for (int q = 0; q < 4; ++q) {
        int cr = kg * 4 + q;
        int s2 = i0 + w * 16 + cr;
        int r2 = __shfl(row, cr, 64);
        float iv = __shfl(inv, cr, 64);
        if (s2 < n_act) {
#pragma unroll
            for (int nt = 0; nt < 4; ++nt) {
                size_t o = (size_t)r2 * DD + nt * 16 + arow;
                op[o] = op[o] + acc[nt][q] * iv;
            }
        }
    }
}

extern "C" void kernel_launch(void* const* d_in, const int* in_sizes, int n_in,
                              void* d_out, int out_size, void* d_ws, size_t ws_size,
                              hipStream_t stream) {
    const float* h   = (const float*)d_in[0];
    const float* vel = (const float*)d_in[1];
    const float* adj = (const float*)d_in[2];
    const int* mask  = (const int*)d_in[3];
    float* out = (float*)d_out;

    char* ws = (char*)d_ws;
    __bf16* ht      = (__bf16*)ws;                       ws += (size_t)BT * DD * NN * 2;
    __bf16* hb16    = (__bf16*)ws;                       ws += (size_t)BT * NN * DD * 2;
    float2* colinfo = (float2*)ws;                       ws += (size_t)BT * NN * 8;
    float* hpart    = (float*)ws;                        ws += (size_t)BT * 8 * DD * 4;
    int* cpart      = (int*)ws;                          ws += (size_t)BT * 8 * 4;
    int* rows       = (int*)ws;

    kpre<<<BT * 8, 256, 0, stream>>>(h, vel, mask, ht, hb16, hpart, cpart, colinfo, rows);
    ktempbeta<<<BB * 32, 256, 0, stream>>>(hb16, mask, hpart, cpart, out);
    kspatial<<<BT * 8, 256, 0, stream>>>(adj, vel, cpart, rows, colinfo, ht, out);
}